// Round 1
// baseline (1753.417 us; speedup 1.0000x reference)
//
#include <hip/hip_runtime.h>
#include <cstdint>
#include <cstddef>

// ---------------------------------------------------------------------------
// Cascade CNN-RNN, fp32 correctness-anchor baseline.
//   per step t (10 steps):
//     conv_step_k : quantize(x[:,t]) -> conv1+clip -> conv2+clip -> a2 [2048][3520]
//     fc3_k       : split-K=8 SGEMM partials P[8][2048][256]
//     mgu_k       : a3 = clip(sum P), hq = quantize(hx), gates, hx update
//   fc5_k: out = hx @ fc5_w.T
// ---------------------------------------------------------------------------

#define NBATCH 2048

// ---------------- fused conv1 + conv2 ----------------
// block: 320 threads = 2 batches x (16 groups x 10 h); grid: 1024 blocks
// thread computes, for its (bi, g, h): conv1 oc1=g row (11 outs),
// then conv2 oc={2g,2g+1} rows (22 outs).
__global__ __launch_bounds__(320) void conv_step_k(
    const float* __restrict__ x, const float* __restrict__ w1g,
    const float* __restrict__ w2g, float* __restrict__ a2, int t)
{
    // halo-padded tiles: rows 0..11 (input rows -1..10), cols 0..12 (in cols -1..11)
    __shared__ float xq_s[2 * 12 * 20];        // [bi][row][col], stride 20
    __shared__ float a1_s[2 * 16 * 12 * 20];   // [bi][ic][row][col]
    __shared__ float w1_s[144];                // [oc1][kk]
    __shared__ float w2_s[32 * 148];           // [oc]*148 + kk*16 + ic (pad for banks)

    const int tid = threadIdx.x;
    const int b0  = blockIdx.x * 2;
    const int bi  = tid / 160;
    const int r   = tid % 160;
    const int g   = r / 10;      // 0..15
    const int h   = r % 10;

    // phase 0: quantized input tile (zero halo), zero a1, stage weights
    for (int i = tid; i < 2 * 12 * 20; i += 320) {
        int bb = i / 240, rem = i % 240, rr = rem / 20, c = rem % 20;
        float v = 0.f;
        if (rr >= 1 && rr <= 10 && c >= 1 && c <= 11) {
            float xv = x[(size_t)(b0 + bb) * 1100 + t * 110 + (rr - 1) * 11 + (c - 1)];
            xv = fminf(fmaxf(xv, -1.f), 1.f);
            v  = rintf(xv * 128.f) * 0.0078125f;   // quantize fwd = q
        }
        xq_s[i] = v;
    }
    for (int i = tid; i < 2 * 16 * 12 * 20; i += 320) a1_s[i] = 0.f;
    if (tid < 144) w1_s[tid] = w1g[tid];
    for (int i = tid; i < 32 * 144; i += 320) {
        int oc = i / 144, rem = i % 144, kk = rem / 16, ic = rem % 16;
        w2_s[oc * 148 + kk * 16 + ic] = w2g[(oc * 16 + ic) * 9 + kk];
    }
    __syncthreads();

    // conv1: out(h,w) = clip( sum_kh,kw xq[h+kh][w+kw] * w1[kh][kw], 0, 1 )
    {
        float acc[11];
#pragma unroll
        for (int w = 0; w < 11; ++w) acc[w] = 0.f;
#pragma unroll
        for (int kh = 0; kh < 3; ++kh) {
            float av[16];
            const float* row = &xq_s[(bi * 12 + h + kh) * 20];
#pragma unroll
            for (int j = 0; j < 4; ++j)
                *(float4*)&av[j * 4] = *(const float4*)&row[j * 4];
#pragma unroll
            for (int kw = 0; kw < 3; ++kw) {
                float wv = w1_s[g * 9 + kh * 3 + kw];
#pragma unroll
                for (int w = 0; w < 11; ++w) acc[w] += av[w + kw] * wv;
            }
        }
        float* dst = &a1_s[((bi * 16 + g) * 12 + h + 1) * 20 + 1];
#pragma unroll
        for (int w = 0; w < 11; ++w) dst[w] = fminf(fmaxf(acc[w], 0.f), 1.f);
    }
    __syncthreads();

    // conv2: 2 output channels per thread
    {
        float acc[2][11];
#pragma unroll
        for (int oi = 0; oi < 2; ++oi)
#pragma unroll
            for (int w = 0; w < 11; ++w) acc[oi][w] = 0.f;

        for (int ic = 0; ic < 16; ++ic) {
#pragma unroll
            for (int kh = 0; kh < 3; ++kh) {
                float av[16];
                const float* row = &a1_s[((bi * 16 + ic) * 12 + h + kh) * 20];
#pragma unroll
                for (int j = 0; j < 4; ++j)
                    *(float4*)&av[j * 4] = *(const float4*)&row[j * 4];
#pragma unroll
                for (int oi = 0; oi < 2; ++oi) {
                    const float* wp = &w2_s[(g * 2 + oi) * 148 + kh * 48];
#pragma unroll
                    for (int kw = 0; kw < 3; ++kw) {
                        float wv = wp[kw * 16 + ic];
#pragma unroll
                        for (int w = 0; w < 11; ++w) acc[oi][w] += av[w + kw] * wv;
                    }
                }
            }
        }
#pragma unroll
        for (int oi = 0; oi < 2; ++oi) {
            float* dst = &a2[(size_t)(b0 + bi) * 3520 + (g * 2 + oi) * 110 + h * 11];
#pragma unroll
            for (int w = 0; w < 11; ++w)
                dst[w] = fminf(fmaxf(acc[oi][w], 0.f), 1.f);
        }
    }
}

// ---------------- fc3: split-K SGEMM ----------------
// C[2048,256] = A[2048,3520] * W[256,3520]^T  (partials over 8 K-chunks of 440)
// BM=128, BN=64, BK=40, 128 threads, 8x8 micro-tile. grid (16,4,8).
#define AS_STRIDE 140
#define BS_STRIDE 76
__global__ __launch_bounds__(128) void fc3_k(
    const float* __restrict__ A, const float* __restrict__ W,
    float* __restrict__ P)
{
    __shared__ float As[40 * AS_STRIDE];
    __shared__ float Bs[40 * BS_STRIDE];
    const int tid  = threadIdx.x;
    const int bm   = blockIdx.x, bn = blockIdx.y, s = blockIdx.z;
    const int row0 = bm * 128, col0 = bn * 64;
    const int ty   = tid / 8, tx = tid % 8;

    float acc[8][8];
#pragma unroll
    for (int i = 0; i < 8; ++i)
#pragma unroll
        for (int j = 0; j < 8; ++j) acc[i][j] = 0.f;

    for (int kt = 0; kt < 11; ++kt) {
        const int kb = s * 440 + kt * 40;
        // stage A tile (128 rows x 40 k) transposed into As[k][r]
#pragma unroll
        for (int it = 0; it < 10; ++it) {
            int f  = tid + it * 128;
            int rr = f / 10, kf = f % 10;
            float4 v = *(const float4*)&A[(size_t)(row0 + rr) * 3520 + kb + kf * 4];
            As[(kf * 4 + 0) * AS_STRIDE + rr] = v.x;
            As[(kf * 4 + 1) * AS_STRIDE + rr] = v.y;
            As[(kf * 4 + 2) * AS_STRIDE + rr] = v.z;
            As[(kf * 4 + 3) * AS_STRIDE + rr] = v.w;
        }
        // stage W tile (64 rows x 40 k) into Bs[k][c]
#pragma unroll
        for (int it = 0; it < 5; ++it) {
            int f  = tid + it * 128;
            int cc = f / 10, kf = f % 10;
            float4 v = *(const float4*)&W[(size_t)(col0 + cc) * 3520 + kb + kf * 4];
            Bs[(kf * 4 + 0) * BS_STRIDE + cc] = v.x;
            Bs[(kf * 4 + 1) * BS_STRIDE + cc] = v.y;
            Bs[(kf * 4 + 2) * BS_STRIDE + cc] = v.z;
            Bs[(kf * 4 + 3) * BS_STRIDE + cc] = v.w;
        }
        __syncthreads();
#pragma unroll 4
        for (int k = 0; k < 40; ++k) {
            float a[8], b[8];
            *(float4*)&a[0] = *(const float4*)&As[k * AS_STRIDE + ty * 8];
            *(float4*)&a[4] = *(const float4*)&As[k * AS_STRIDE + ty * 8 + 4];
            *(float4*)&b[0] = *(const float4*)&Bs[k * BS_STRIDE + tx * 8];
            *(float4*)&b[4] = *(const float4*)&Bs[k * BS_STRIDE + tx * 8 + 4];
#pragma unroll
            for (int i = 0; i < 8; ++i)
#pragma unroll
                for (int j = 0; j < 8; ++j) acc[i][j] += a[i] * b[j];
        }
        __syncthreads();
    }
    float* p = P + ((size_t)s * 2048 + row0) * 256 + col0;
#pragma unroll
    for (int i = 0; i < 8; ++i) {
        float4 v0, v1;
        v0.x = acc[i][0]; v0.y = acc[i][1]; v0.z = acc[i][2]; v0.w = acc[i][3];
        v1.x = acc[i][4]; v1.y = acc[i][5]; v1.z = acc[i][6]; v1.w = acc[i][7];
        *(float4*)&p[(size_t)(ty * 8 + i) * 256 + tx * 8]     = v0;
        *(float4*)&p[(size_t)(ty * 8 + i) * 256 + tx * 8 + 4] = v1;
    }
}

// ---------------- MGU cell (fuses split-K reduce + clip) ----------------
// block = 128 threads (one per gate row), grid = 2048 (one per batch)
__global__ __launch_bounds__(128) void mgu_k(
    const float* __restrict__ P, const float* __restrict__ wih,
    const float* __restrict__ whh, float* __restrict__ hx)
{
    __shared__ float a3_s[256];
    __shared__ float hq_s[64];
    __shared__ float gi_s[128], gh_s[128];
    const int b = blockIdx.x, tid = threadIdx.x;

    for (int i = tid; i < 256; i += 128) {
        float v = 0.f;
#pragma unroll
        for (int s = 0; s < 8; ++s) v += P[(size_t)s * 524288 + b * 256 + i];
        a3_s[i] = fminf(fmaxf(v, 0.f), 1.f);
    }
    if (tid < 64) {
        float v = hx[b * 64 + tid];
        v = fminf(fmaxf(v, -1.f), 1.f);
        hq_s[tid] = rintf(v * 128.f) * 0.0078125f;
    }
    __syncthreads();
    {
        float gi = 0.f;
        const float* wr = &wih[(size_t)tid * 256];
        for (int k = 0; k < 256; k += 4) {
            float4 wv = *(const float4*)&wr[k];
            gi += a3_s[k] * wv.x + a3_s[k + 1] * wv.y + a3_s[k + 2] * wv.z + a3_s[k + 3] * wv.w;
        }
        float gh = 0.f;
        const float* hr = &whh[(size_t)tid * 64];
#pragma unroll
        for (int k = 0; k < 64; k += 4) {
            float4 wv = *(const float4*)&hr[k];
            gh += hq_s[k] * wv.x + hq_s[k + 1] * wv.y + hq_s[k + 2] * wv.z + hq_s[k + 3] * wv.w;
        }
        gi_s[tid] = gi;
        gh_s[tid] = gh;
    }
    __syncthreads();
    if (tid < 64) {
        float f = 0.5f * (gi_s[tid] + gh_s[tid]) + 0.5f;
        f = fminf(fmaxf(f, 0.f), 1.f);               // hard sigmoid
        float n = gi_s[64 + tid] + f * gh_s[64 + tid];
        n = fminf(fmaxf(n, -1.f), 1.f);              // hard tanh
        hx[b * 64 + tid] = (1.f - f) * n + f * hq_s[tid];
    }
}

// ---------------- fc5 ----------------
__global__ __launch_bounds__(256) void fc5_k(
    const float* __restrict__ hx, const float* __restrict__ w,
    float* __restrict__ out)
{
    int idx = blockIdx.x * 256 + threadIdx.x;
    if (idx < 2048 * 7) {
        int b = idx / 7, c = idx % 7;
        const float* hr = &hx[b * 64];
        const float* wr = &w[c * 64];
        float acc = 0.f;
#pragma unroll
        for (int k = 0; k < 64; ++k) acc += hr[k] * wr[k];
        out[idx] = acc;
    }
}

extern "C" void kernel_launch(void* const* d_in, const int* in_sizes, int n_in,
                              void* d_out, int out_size, void* d_ws, size_t ws_size,
                              hipStream_t stream)
{
    const float* x    = (const float*)d_in[0];
    const float* w1   = (const float*)d_in[1];
    const float* w2   = (const float*)d_in[2];
    const float* fc3w = (const float*)d_in[3];
    const float* wih  = (const float*)d_in[4];
    const float* whh  = (const float*)d_in[5];
    const float* fc5w = (const float*)d_in[6];
    float* out = (float*)d_out;

    float* ws = (float*)d_ws;
    float* a2 = ws;                               // 2048*3520      = 7,208,960 f
    float* P  = a2 + (size_t)2048 * 3520;         // 8*2048*256     = 4,194,304 f
    float* hx = P + (size_t)8 * 2048 * 256;       // 2048*64        =   131,072 f

    hipMemsetAsync(hx, 0, (size_t)2048 * 64 * sizeof(float), stream);

    for (int t = 0; t < 10; ++t) {
        conv_step_k<<<1024, 320, 0, stream>>>(x, w1, w2, a2, t);
        fc3_k<<<dim3(16, 4, 8), 128, 0, stream>>>(a2, fc3w, P);
        mgu_k<<<2048, 128, 0, stream>>>(P, wih, whh, hx);
    }
    fc5_k<<<56, 256, 0, stream>>>(hx, fc5w, out);
}

// Round 2
// 1108.253 us; speedup vs baseline: 1.5821x; 1.5821x over previous
//
#include <hip/hip_runtime.h>
#include <hip/hip_bf16.h>
#include <cstdint>
#include <cstddef>

// ---------------------------------------------------------------------------
// R2: fc3 -> bf16 MFMA (16x16x32), conv emits bf16 a2, fc3_w converted once.
//   per step t (10 steps):
//     conv_step_k : quantize(x[:,t]) -> conv1+clip -> conv2+clip -> a2 bf16
//     fc3_mfma_k  : split-K=11 partials P[11][2048][256] fp32 via MFMA
//     mgu_k       : a3 = clip(sum P), hq = quantize(hx), gates, hx update
//   fc5_k: out = hx @ fc5_w.T
// ---------------------------------------------------------------------------

typedef __bf16 bf16x8v __attribute__((ext_vector_type(8)));
typedef float  f32x4   __attribute__((ext_vector_type(4)));

// ---------------- weight convert fp32 -> bf16 ----------------
__global__ __launch_bounds__(256) void cvt_k(
    const float* __restrict__ in, __hip_bfloat16* __restrict__ out, int n)
{
    int i = (blockIdx.x * 256 + threadIdx.x) * 4;
    if (i < n) {
        float4 v = *(const float4*)&in[i];
        out[i + 0] = __float2bfloat16(v.x);
        out[i + 1] = __float2bfloat16(v.y);
        out[i + 2] = __float2bfloat16(v.z);
        out[i + 3] = __float2bfloat16(v.w);
    }
}

// ---------------- fused conv1 + conv2 (bf16 output) ----------------
// block: 320 threads = 2 batches x (16 groups x 10 h); grid: 1024 blocks
__global__ __launch_bounds__(320) void conv_step_k(
    const float* __restrict__ x, const float* __restrict__ w1g,
    const float* __restrict__ w2g, __hip_bfloat16* __restrict__ a2, int t)
{
    __shared__ float xq_s[2 * 12 * 20];        // [bi][row][col], stride 20
    __shared__ float a1_s[2 * 16 * 12 * 20];   // [bi][ic][row][col]
    __shared__ float w1_s[144];                // [oc1][kk]
    __shared__ float w2_s[32 * 148];           // [oc]*148 + kk*16 + ic

    const int tid = threadIdx.x;
    const int b0  = blockIdx.x * 2;
    const int bi  = tid / 160;
    const int r   = tid % 160;
    const int g   = r / 10;      // 0..15
    const int h   = r % 10;

    for (int i = tid; i < 2 * 12 * 20; i += 320) {
        int bb = i / 240, rem = i % 240, rr = rem / 20, c = rem % 20;
        float v = 0.f;
        if (rr >= 1 && rr <= 10 && c >= 1 && c <= 11) {
            float xv = x[(size_t)(b0 + bb) * 1100 + t * 110 + (rr - 1) * 11 + (c - 1)];
            xv = fminf(fmaxf(xv, -1.f), 1.f);
            v  = rintf(xv * 128.f) * 0.0078125f;   // quantize fwd = q
        }
        xq_s[i] = v;
    }
    for (int i = tid; i < 2 * 16 * 12 * 20; i += 320) a1_s[i] = 0.f;
    if (tid < 144) w1_s[tid] = w1g[tid];
    for (int i = tid; i < 32 * 144; i += 320) {
        int oc = i / 144, rem = i % 144, kk = rem / 16, ic = rem % 16;
        w2_s[oc * 148 + kk * 16 + ic] = w2g[(oc * 16 + ic) * 9 + kk];
    }
    __syncthreads();

    // conv1
    {
        float acc[11];
#pragma unroll
        for (int w = 0; w < 11; ++w) acc[w] = 0.f;
#pragma unroll
        for (int kh = 0; kh < 3; ++kh) {
            float av[16];
            const float* row = &xq_s[(bi * 12 + h + kh) * 20];
#pragma unroll
            for (int j = 0; j < 4; ++j)
                *(float4*)&av[j * 4] = *(const float4*)&row[j * 4];
#pragma unroll
            for (int kw = 0; kw < 3; ++kw) {
                float wv = w1_s[g * 9 + kh * 3 + kw];
#pragma unroll
                for (int w = 0; w < 11; ++w) acc[w] += av[w + kw] * wv;
            }
        }
        float* dst = &a1_s[((bi * 16 + g) * 12 + h + 1) * 20 + 1];
#pragma unroll
        for (int w = 0; w < 11; ++w) dst[w] = fminf(fmaxf(acc[w], 0.f), 1.f);
    }
    __syncthreads();

    // conv2: 2 output channels per thread, bf16 store
    {
        float acc[2][11];
#pragma unroll
        for (int oi = 0; oi < 2; ++oi)
#pragma unroll
            for (int w = 0; w < 11; ++w) acc[oi][w] = 0.f;

        for (int ic = 0; ic < 16; ++ic) {
#pragma unroll
            for (int kh = 0; kh < 3; ++kh) {
                float av[16];
                const float* row = &a1_s[((bi * 16 + ic) * 12 + h + kh) * 20];
#pragma unroll
                for (int j = 0; j < 4; ++j)
                    *(float4*)&av[j * 4] = *(const float4*)&row[j * 4];
#pragma unroll
                for (int oi = 0; oi < 2; ++oi) {
                    const float* wp = &w2_s[(g * 2 + oi) * 148 + kh * 48];
#pragma unroll
                    for (int kw = 0; kw < 3; ++kw) {
                        float wv = wp[kw * 16 + ic];
#pragma unroll
                        for (int w = 0; w < 11; ++w) acc[oi][w] += av[w + kw] * wv;
                    }
                }
            }
        }
#pragma unroll
        for (int oi = 0; oi < 2; ++oi) {
            __hip_bfloat16* dst = &a2[(size_t)(b0 + bi) * 3520 + (g * 2 + oi) * 110 + h * 11];
#pragma unroll
            for (int w = 0; w < 11; ++w)
                dst[w] = __float2bfloat16(fminf(fmaxf(acc[oi][w], 0.f), 1.f));
        }
    }
}

// ---------------- fc3: bf16 MFMA split-K GEMM ----------------
// P[s][2048][256] partial = A[2048, s*320 : (s+1)*320] * W^T chunk
// 64x64 tile, 4 waves (2x2 of 32x32), BK=64, 5 K-steps. grid (32,4,11).
// LDS tiles [64 rows][64 bf16] with chunk-XOR swizzle: LDS[r][u*8..] holds
// A[r][(u ^ (r&7))*8..]; staged via global_load_lds w/ pre-swizzled source.
#define FC3_KC 320
#define FC3_SPLITS 11
__global__ __launch_bounds__(256) void fc3_mfma_k(
    const __hip_bfloat16* __restrict__ A,   // [2048][3520]
    const __hip_bfloat16* __restrict__ W,   // [256][3520]
    float* __restrict__ P)                  // [11][2048][256]
{
    __shared__ __hip_bfloat16 As[64 * 64];
    __shared__ __hip_bfloat16 Bs[64 * 64];

    const int tid  = threadIdx.x;
    const int wv   = tid >> 6;          // wave 0..3
    const int lane = tid & 63;
    const int m0 = blockIdx.x * 64, n0 = blockIdx.y * 64, s = blockIdx.z;
    const int wr = wv >> 1, wc = wv & 1; // wave's 32x32 sub-tile

    const int srow   = lane >> 3;       // 0..7 (row within 8-row stage group)
    const int schunk = lane & 7;        // 0..7 (16B chunk within 128B row)
    const int swzc   = schunk ^ srow;   // pre-swizzled source chunk

    const int fr = lane & 15;           // fragment row/col
    const int fq = lane >> 4;           // k-subgroup 0..3

    f32x4 zero = {0.f, 0.f, 0.f, 0.f};
    f32x4 acc[2][2];
    acc[0][0] = zero; acc[0][1] = zero; acc[1][0] = zero; acc[1][1] = zero;

    for (int kt = 0; kt < FC3_KC / 64; ++kt) {
        const int kb = s * FC3_KC + kt * 64;  // bf16 index into K
        // stage: wave wv stages tile rows [wv*16, wv*16+16) of both A and W,
        // 8 rows (1 KiB) per global_load_lds instruction.
#pragma unroll
        for (int i = 0; i < 2; ++i) {
            const int tr = wv * 16 + i * 8;            // tile row base (uniform)
            const __hip_bfloat16* srcA =
                A + (size_t)(m0 + tr + srow) * 3520 + kb + swzc * 8;
            __builtin_amdgcn_global_load_lds(
                (const __attribute__((address_space(1))) void*)srcA,
                (__attribute__((address_space(3))) void*)&As[tr * 64], 16, 0, 0);
            const __hip_bfloat16* srcB =
                W + (size_t)(n0 + tr + srow) * 3520 + kb + swzc * 8;
            __builtin_amdgcn_global_load_lds(
                (const __attribute__((address_space(1))) void*)srcB,
                (__attribute__((address_space(3))) void*)&Bs[tr * 64], 16, 0, 0);
        }
        __syncthreads();   // drains vmcnt -> staged data visible

#pragma unroll
        for (int kk = 0; kk < 2; ++kk) {
            bf16x8v af[2], bfv[2];
#pragma unroll
            for (int mi = 0; mi < 2; ++mi) {
                const int rr = wr * 32 + mi * 16 + fr;
                const int cc = (kk * 4 + fq) ^ (rr & 7);
                af[mi] = *(const bf16x8v*)&As[rr * 64 + cc * 8];
            }
#pragma unroll
            for (int ni = 0; ni < 2; ++ni) {
                const int rr = wc * 32 + ni * 16 + fr;
                const int cc = (kk * 4 + fq) ^ (rr & 7);
                bfv[ni] = *(const bf16x8v*)&Bs[rr * 64 + cc * 8];
            }
#pragma unroll
            for (int mi = 0; mi < 2; ++mi)
#pragma unroll
                for (int ni = 0; ni < 2; ++ni)
                    acc[mi][ni] = __builtin_amdgcn_mfma_f32_16x16x32_bf16(
                        af[mi], bfv[ni], acc[mi][ni], 0, 0, 0);
        }
        __syncthreads();
    }

    // C/D layout: col = lane&15, row = (lane>>4)*4 + reg
    float* p = P + (size_t)s * (2048 * 256)
                 + (size_t)(m0 + wr * 32) * 256 + (n0 + wc * 32);
#pragma unroll
    for (int mi = 0; mi < 2; ++mi)
#pragma unroll
        for (int ni = 0; ni < 2; ++ni)
#pragma unroll
            for (int j = 0; j < 4; ++j)
                p[(size_t)(mi * 16 + fq * 4 + j) * 256 + ni * 16 + fr] = acc[mi][ni][j];
}

// ---------------- MGU cell (fuses split-K reduce + clip) ----------------
__global__ __launch_bounds__(128) void mgu_k(
    const float* __restrict__ P, const float* __restrict__ wih,
    const float* __restrict__ whh, float* __restrict__ hx)
{
    __shared__ float a3_s[256];
    __shared__ float hq_s[64];
    __shared__ float gi_s[128], gh_s[128];
    const int b = blockIdx.x, tid = threadIdx.x;

    for (int i = tid; i < 256; i += 128) {
        float v = 0.f;
#pragma unroll
        for (int s = 0; s < FC3_SPLITS; ++s) v += P[(size_t)s * 524288 + b * 256 + i];
        a3_s[i] = fminf(fmaxf(v, 0.f), 1.f);
    }
    if (tid < 64) {
        float v = hx[b * 64 + tid];
        v = fminf(fmaxf(v, -1.f), 1.f);
        hq_s[tid] = rintf(v * 128.f) * 0.0078125f;
    }
    __syncthreads();
    {
        float gi = 0.f;
        const float* wr = &wih[(size_t)tid * 256];
        for (int k = 0; k < 256; k += 4) {
            float4 wv = *(const float4*)&wr[k];
            gi += a3_s[k] * wv.x + a3_s[k + 1] * wv.y + a3_s[k + 2] * wv.z + a3_s[k + 3] * wv.w;
        }
        float gh = 0.f;
        const float* hr = &whh[(size_t)tid * 64];
#pragma unroll
        for (int k = 0; k < 64; k += 4) {
            float4 wv = *(const float4*)&hr[k];
            gh += hq_s[k] * wv.x + hq_s[k + 1] * wv.y + hq_s[k + 2] * wv.z + hq_s[k + 3] * wv.w;
        }
        gi_s[tid] = gi;
        gh_s[tid] = gh;
    }
    __syncthreads();
    if (tid < 64) {
        float f = 0.5f * (gi_s[tid] + gh_s[tid]) + 0.5f;
        f = fminf(fmaxf(f, 0.f), 1.f);               // hard sigmoid
        float n = gi_s[64 + tid] + f * gh_s[64 + tid];
        n = fminf(fmaxf(n, -1.f), 1.f);              // hard tanh
        hx[b * 64 + tid] = (1.f - f) * n + f * hq_s[tid];
    }
}

// ---------------- fc5 ----------------
__global__ __launch_bounds__(256) void fc5_k(
    const float* __restrict__ hx, const float* __restrict__ w,
    float* __restrict__ out)
{
    int idx = blockIdx.x * 256 + threadIdx.x;
    if (idx < 2048 * 7) {
        int b = idx / 7, c = idx % 7;
        const float* hr = &hx[b * 64];
        const float* wr = &w[c * 64];
        float acc = 0.f;
#pragma unroll
        for (int k = 0; k < 64; ++k) acc += hr[k] * wr[k];
        out[idx] = acc;
    }
}

extern "C" void kernel_launch(void* const* d_in, const int* in_sizes, int n_in,
                              void* d_out, int out_size, void* d_ws, size_t ws_size,
                              hipStream_t stream)
{
    const float* x    = (const float*)d_in[0];
    const float* w1   = (const float*)d_in[1];
    const float* w2   = (const float*)d_in[2];
    const float* fc3w = (const float*)d_in[3];
    const float* wih  = (const float*)d_in[4];
    const float* whh  = (const float*)d_in[5];
    const float* fc5w = (const float*)d_in[6];
    float* out = (float*)d_out;

    char* ws = (char*)d_ws;
    __hip_bfloat16* a2 = (__hip_bfloat16*)ws;                 // 2048*3520*2 = 14,417,920 B
    float* P  = (float*)(ws + 14417920);                      // 11*2048*256*4 = 23,068,672 B
    float* hx = (float*)(ws + 14417920 + 23068672);           // 524,288 B
    __hip_bfloat16* w3 = (__hip_bfloat16*)(ws + 14417920 + 23068672 + 524288); // 1,802,240 B

    cvt_k<<<880, 256, 0, stream>>>(fc3w, w3, 256 * 3520);
    hipMemsetAsync(hx, 0, (size_t)2048 * 64 * sizeof(float), stream);

    for (int t = 0; t < 10; ++t) {
        conv_step_k<<<1024, 320, 0, stream>>>(x, w1, w2, a2, t);
        fc3_mfma_k<<<dim3(32, 4, FC3_SPLITS), 256, 0, stream>>>(a2, w3, P);
        mgu_k<<<2048, 128, 0, stream>>>(P, wih, whh, hx);
    }
    fc5_k<<<56, 256, 0, stream>>>(hx, fc5w, out);
}

// Round 3
// 598.154 us; speedup vs baseline: 2.9314x; 1.8528x over previous
//
#include <hip/hip_runtime.h>
#include <hip/hip_bf16.h>
#include <cstdint>
#include <cstddef>

// ---------------------------------------------------------------------------
// R3: conv2 -> bf16 MFMA via shift-trick (no im2col), wave-private batches,
//     permuted a2p K-layout (kp) shared between conv epilogue and fc3 weights.
//   per step: conv_step_k (quant+conv1 VALU+conv2 MFMA) -> fc3_mfma_k -> mgu_k
// ---------------------------------------------------------------------------

typedef __bf16 bf16x8v __attribute__((ext_vector_type(8)));
typedef float  f32x4   __attribute__((ext_vector_type(4)));

#define WAVE_FENCE() asm volatile("s_waitcnt lgkmcnt(0)" ::: "memory")

// a1 LDS layout: [12 rows][13 cols][24 elems] bf16 (16 ic used + 8 pad), per batch
#define A1_PS 24
#define A1_RS (13 * A1_PS)          // 312
#define A1_ZS (12 * A1_RS)          // 3744 = zero slot (16 zeros)
#define A1_BS 3776                  // per-batch elems (7552 B)
#define XQ_BS 176                   // padded [12][14] f32 + pad

#define FC3_K      3584             // permuted/padded K (7 Mtiles * 512)
#define FC3_KC     448
#define FC3_SPLITS 8

// ---------------- weight converts (run once per call) ----------------
// fc3 weights into permuted K-layout kp = mt*512 + (fq*16+col)*8 + nt*4 + j
__global__ __launch_bounds__(256) void cvt_w3p_k(
    const float* __restrict__ in, __hip_bfloat16* __restrict__ out)
{
    int idx = blockIdx.x * 256 + threadIdx.x;          // < 256*3584
    int n = idx / FC3_K, kp = idx % FC3_K;
    int mt = kp >> 9, r = kp & 511;
    int fq = r >> 7, col = (r >> 3) & 15, nt = (r >> 2) & 1, j = r & 3;
    int pixel = mt * 16 + fq * 4 + j, oc = nt * 16 + col;
    float v = (pixel < 110) ? in[n * 3520 + oc * 110 + pixel] : 0.f;
    out[idx] = __float2bfloat16(v);
}

// conv2 weights: w2p[oc][koff*16+ic], padded to 160 with zeros (koff 9)
__global__ __launch_bounds__(256) void cvt_w2p_k(
    const float* __restrict__ w2g, __hip_bfloat16* __restrict__ out)
{
    int idx = blockIdx.x * 256 + threadIdx.x;          // < 5120
    int oc = idx / 160, k = idx % 160;
    int koff = k >> 4, ic = k & 15;
    float v = (koff < 9) ? w2g[(oc * 16 + ic) * 9 + koff] : 0.f;
    out[idx] = __float2bfloat16(v);
}

// ---------------- fused quant + conv1 (VALU) + conv2 (MFMA) ----------------
// block = 256 thr = 4 waves; wave = 1 batch (fully private, no barriers).
// grid = 512 -> 2048 batches.
__global__ __launch_bounds__(256) void conv_step_k(
    const float* __restrict__ x, const float* __restrict__ w1g,
    const __hip_bfloat16* __restrict__ w2p,
    __hip_bfloat16* __restrict__ a2p, int t)
{
    __shared__ __hip_bfloat16 a1_s[4 * A1_BS];
    __shared__ float xq_s[4 * XQ_BS];

    const int tid  = threadIdx.x;
    const int wv   = tid >> 6, lane = tid & 63;
    const int b    = blockIdx.x * 4 + wv;
    const int ab   = wv * A1_BS;
    const int xb   = wv * XQ_BS;

    const int fr  = lane & 15, fq = lane >> 4;
    const int fqh = fq >> 1,  icb = (fq & 1) * 8;

    // hoist conv2 B-fragments: [kt][nt], oc = nt*16+fr, k = kt*32 + fq*8
    bf16x8v bfrag[5][2];
#pragma unroll
    for (int kt = 0; kt < 5; ++kt)
#pragma unroll
        for (int nt = 0; nt < 2; ++nt)
            bfrag[kt][nt] = *(const bf16x8v*)&w2p[(nt * 16 + fr) * 160 + kt * 32 + fq * 8];

    // hoist conv1 weights: lane covers oc pair (2*ocp, 2*ocp+1)
    const int ocp = lane >> 3, pg = lane & 7;
    float w1a[9], w1b[9];
#pragma unroll
    for (int k = 0; k < 9; ++k) {
        w1a[k] = w1g[(2 * ocp) * 9 + k];
        w1b[k] = w1g[(2 * ocp + 1) * 9 + k];
    }

    // zero a1 (incl. halo + zero slot) and xq (halo)
    {
        bf16x8v z = {};
#pragma unroll
        for (int i = 0; i < 8; ++i) {
            int c = lane + i * 64;
            if (c < A1_BS / 8) *(bf16x8v*)&a1_s[ab + c * 8] = z;
        }
        float4 zf = {0.f, 0.f, 0.f, 0.f};
        if (lane < XQ_BS / 4) *(float4*)&xq_s[xb + lane * 4] = zf;
    }
    WAVE_FENCE();

    // stage quantized input window
#pragma unroll
    for (int pass = 0; pass < 2; ++pass) {
        int p = pass * 64 + lane;
        if (p < 110) {
            float xv = x[(size_t)b * 1100 + t * 110 + p];
            xv = fminf(fmaxf(xv, -1.f), 1.f);
            xv = rintf(xv * 128.f) * 0.0078125f;
            int h = p / 11, w = p - h * 11;
            xq_s[xb + (h + 1) * 14 + (w + 1)] = xv;
        }
    }
    WAVE_FENCE();

    // conv1: each lane: 2 ocs x 14 pixels
#pragma unroll 2
    for (int i = 0; i < 14; ++i) {
        int p = pg * 14 + i;
        if (p < 110) {
            int h = p / 11, w = p - h * 11;
            const float* xw = &xq_s[xb + h * 14 + w];
            float a0 = 0.f, a1v = 0.f;
#pragma unroll
            for (int dr = 0; dr < 3; ++dr)
#pragma unroll
                for (int dc = 0; dc < 3; ++dc) {
                    float sv = xw[dr * 14 + dc];
                    a0  += w1a[dr * 3 + dc] * sv;
                    a1v += w1b[dr * 3 + dc] * sv;
                }
            a0  = fminf(fmaxf(a0, 0.f), 1.f);
            a1v = fminf(fmaxf(a1v, 0.f), 1.f);
            __hip_bfloat162 pr;
            pr.x = __float2bfloat16(a0);
            pr.y = __float2bfloat16(a1v);
            *(__hip_bfloat162*)&a1_s[ab + (h + 1) * A1_RS + (w + 1) * A1_PS + 2 * ocp] = pr;
        }
    }
    WAVE_FENCE();

    // conv2 MFMA: M = pixels (7 tiles of 16), N = 32 oc (2 tiles), K = 160 (5 kt)
    // per-lane shifted-read offsets (koff = 2*kt + fqh -> (kh,kw))
    const int d0 = fqh * 24 + icb;                    // (0,0)/(0,1)
    const int d1 = (fqh ? 312 : 48) + icb;            // (0,2)/(1,0)
    const int d2 = 336 + fqh * 24 + icb;              // (1,1)/(1,2)
    const int d3 = 624 + fqh * 24 + icb;              // (2,0)/(2,1)

#pragma unroll
    for (int m = 0; m < 7; ++m) {
        int p = m * 16 + fr; if (p > 109) p = 109;
        int h = p / 11, w = p - h * 11;
        const int bm = ab + h * A1_RS + w * A1_PS;
        f32x4 acc0 = {0.f, 0.f, 0.f, 0.f}, acc1 = {0.f, 0.f, 0.f, 0.f};
        bf16x8v a;
        a = *(const bf16x8v*)&a1_s[bm + d0];
        acc0 = __builtin_amdgcn_mfma_f32_16x16x32_bf16(a, bfrag[0][0], acc0, 0, 0, 0);
        acc1 = __builtin_amdgcn_mfma_f32_16x16x32_bf16(a, bfrag[0][1], acc1, 0, 0, 0);
        a = *(const bf16x8v*)&a1_s[bm + d1];
        acc0 = __builtin_amdgcn_mfma_f32_16x16x32_bf16(a, bfrag[1][0], acc0, 0, 0, 0);
        acc1 = __builtin_amdgcn_mfma_f32_16x16x32_bf16(a, bfrag[1][1], acc1, 0, 0, 0);
        a = *(const bf16x8v*)&a1_s[bm + d2];
        acc0 = __builtin_amdgcn_mfma_f32_16x16x32_bf16(a, bfrag[2][0], acc0, 0, 0, 0);
        acc1 = __builtin_amdgcn_mfma_f32_16x16x32_bf16(a, bfrag[2][1], acc1, 0, 0, 0);
        a = *(const bf16x8v*)&a1_s[bm + d3];
        acc0 = __builtin_amdgcn_mfma_f32_16x16x32_bf16(a, bfrag[3][0], acc0, 0, 0, 0);
        acc1 = __builtin_amdgcn_mfma_f32_16x16x32_bf16(a, bfrag[3][1], acc1, 0, 0, 0);
        a = *(const bf16x8v*)&a1_s[fqh ? (ab + A1_ZS) : (bm + 672 + icb)];
        acc0 = __builtin_amdgcn_mfma_f32_16x16x32_bf16(a, bfrag[4][0], acc0, 0, 0, 0);
        acc1 = __builtin_amdgcn_mfma_f32_16x16x32_bf16(a, bfrag[4][1], acc1, 0, 0, 0);

        // C layout: row = fq*4+j (pixel), col = fr (oc). Store permuted kp slot.
        bf16x8v ov;
#pragma unroll
        for (int j = 0; j < 4; ++j) {
            bool valid = (m * 16 + fq * 4 + j) < 110;
            float v0 = valid ? fminf(fmaxf(acc0[j], 0.f), 1.f) : 0.f;
            float v1 = valid ? fminf(fmaxf(acc1[j], 0.f), 1.f) : 0.f;
            ov[j]     = (__bf16)v0;
            ov[4 + j] = (__bf16)v1;
        }
        *(bf16x8v*)&a2p[(size_t)b * FC3_K + m * 512 + lane * 8] = ov;
    }
}

// ---------------- fc3: bf16 MFMA split-K GEMM (K = 3584 permuted) ----------
// 64x64 tile, 4 waves, BK=64, 7 K-steps. grid (32,4,8).
__global__ __launch_bounds__(256) void fc3_mfma_k(
    const __hip_bfloat16* __restrict__ A,   // [2048][3584]
    const __hip_bfloat16* __restrict__ W,   // [256][3584]
    float* __restrict__ P)                  // [8][2048][256]
{
    __shared__ __hip_bfloat16 As[64 * 64];
    __shared__ __hip_bfloat16 Bs[64 * 64];

    const int tid  = threadIdx.x;
    const int wv   = tid >> 6;
    const int lane = tid & 63;
    const int m0 = blockIdx.x * 64, n0 = blockIdx.y * 64, s = blockIdx.z;
    const int wr = wv >> 1, wc = wv & 1;

    const int srow   = lane >> 3;
    const int schunk = lane & 7;
    const int swzc   = schunk ^ srow;

    const int fr = lane & 15;
    const int fq = lane >> 4;

    f32x4 zero = {0.f, 0.f, 0.f, 0.f};
    f32x4 acc[2][2];
    acc[0][0] = zero; acc[0][1] = zero; acc[1][0] = zero; acc[1][1] = zero;

    for (int kt = 0; kt < FC3_KC / 64; ++kt) {
        const int kb = s * FC3_KC + kt * 64;
#pragma unroll
        for (int i = 0; i < 2; ++i) {
            const int tr = wv * 16 + i * 8;
            const __hip_bfloat16* srcA =
                A + (size_t)(m0 + tr + srow) * FC3_K + kb + swzc * 8;
            __builtin_amdgcn_global_load_lds(
                (const __attribute__((address_space(1))) void*)srcA,
                (__attribute__((address_space(3))) void*)&As[tr * 64], 16, 0, 0);
            const __hip_bfloat16* srcB =
                W + (size_t)(n0 + tr + srow) * FC3_K + kb + swzc * 8;
            __builtin_amdgcn_global_load_lds(
                (const __attribute__((address_space(1))) void*)srcB,
                (__attribute__((address_space(3))) void*)&Bs[tr * 64], 16, 0, 0);
        }
        __syncthreads();

#pragma unroll
        for (int kk = 0; kk < 2; ++kk) {
            bf16x8v af[2], bfv[2];
#pragma unroll
            for (int mi = 0; mi < 2; ++mi) {
                const int rr = wr * 32 + mi * 16 + fr;
                const int cc = (kk * 4 + fq) ^ (rr & 7);
                af[mi] = *(const bf16x8v*)&As[rr * 64 + cc * 8];
            }
#pragma unroll
            for (int ni = 0; ni < 2; ++ni) {
                const int rr = wc * 32 + ni * 16 + fr;
                const int cc = (kk * 4 + fq) ^ (rr & 7);
                bfv[ni] = *(const bf16x8v*)&Bs[rr * 64 + cc * 8];
            }
#pragma unroll
            for (int mi = 0; mi < 2; ++mi)
#pragma unroll
                for (int ni = 0; ni < 2; ++ni)
                    acc[mi][ni] = __builtin_amdgcn_mfma_f32_16x16x32_bf16(
                        af[mi], bfv[ni], acc[mi][ni], 0, 0, 0);
        }
        __syncthreads();
    }

    float* p = P + (size_t)s * (2048 * 256)
                 + (size_t)(m0 + wr * 32) * 256 + (n0 + wc * 32);
#pragma unroll
    for (int mi = 0; mi < 2; ++mi)
#pragma unroll
        for (int ni = 0; ni < 2; ++ni)
#pragma unroll
            for (int j = 0; j < 4; ++j)
                p[(size_t)(mi * 16 + fq * 4 + j) * 256 + ni * 16 + fr] = acc[mi][ni][j];
}

// ---------------- MGU cell (fuses split-K reduce + clip) ----------------
__global__ __launch_bounds__(128) void mgu_k(
    const float* __restrict__ P, const float* __restrict__ wih,
    const float* __restrict__ whh, float* __restrict__ hx)
{
    __shared__ float a3_s[256];
    __shared__ float hq_s[64];
    __shared__ float gi_s[128], gh_s[128];
    const int b = blockIdx.x, tid = threadIdx.x;

    for (int i = tid; i < 256; i += 128) {
        float v = 0.f;
#pragma unroll
        for (int s = 0; s < FC3_SPLITS; ++s) v += P[(size_t)s * 524288 + b * 256 + i];
        a3_s[i] = fminf(fmaxf(v, 0.f), 1.f);
    }
    if (tid < 64) {
        float v = hx[b * 64 + tid];
        v = fminf(fmaxf(v, -1.f), 1.f);
        hq_s[tid] = rintf(v * 128.f) * 0.0078125f;
    }
    __syncthreads();
    {
        float gi = 0.f;
        const float* wr = &wih[(size_t)tid * 256];
        for (int k = 0; k < 256; k += 4) {
            float4 wv = *(const float4*)&wr[k];
            gi += a3_s[k] * wv.x + a3_s[k + 1] * wv.y + a3_s[k + 2] * wv.z + a3_s[k + 3] * wv.w;
        }
        float gh = 0.f;
        const float* hr = &whh[(size_t)tid * 64];
#pragma unroll
        for (int k = 0; k < 64; k += 4) {
            float4 wv = *(const float4*)&hr[k];
            gh += hq_s[k] * wv.x + hq_s[k + 1] * wv.y + hq_s[k + 2] * wv.z + hq_s[k + 3] * wv.w;
        }
        gi_s[tid] = gi;
        gh_s[tid] = gh;
    }
    __syncthreads();
    if (tid < 64) {
        float f = 0.5f * (gi_s[tid] + gh_s[tid]) + 0.5f;
        f = fminf(fmaxf(f, 0.f), 1.f);
        float n = gi_s[64 + tid] + f * gh_s[64 + tid];
        n = fminf(fmaxf(n, -1.f), 1.f);
        hx[b * 64 + tid] = (1.f - f) * n + f * hq_s[tid];
    }
}

// ---------------- fc5 ----------------
__global__ __launch_bounds__(256) void fc5_k(
    const float* __restrict__ hx, const float* __restrict__ w,
    float* __restrict__ out)
{
    int idx = blockIdx.x * 256 + threadIdx.x;
    if (idx < 2048 * 7) {
        int b = idx / 7, c = idx % 7;
        const float* hr = &hx[b * 64];
        const float* wr = &w[c * 64];
        float acc = 0.f;
#pragma unroll
        for (int k = 0; k < 64; ++k) acc += hr[k] * wr[k];
        out[idx] = acc;
    }
}

extern "C" void kernel_launch(void* const* d_in, const int* in_sizes, int n_in,
                              void* d_out, int out_size, void* d_ws, size_t ws_size,
                              hipStream_t stream)
{
    const float* x    = (const float*)d_in[0];
    const float* w1   = (const float*)d_in[1];
    const float* w2   = (const float*)d_in[2];
    const float* fc3w = (const float*)d_in[3];
    const float* wih  = (const float*)d_in[4];
    const float* whh  = (const float*)d_in[5];
    const float* fc5w = (const float*)d_in[6];
    float* out = (float*)d_out;

    char* ws = (char*)d_ws;
    __hip_bfloat16* a2p = (__hip_bfloat16*)ws;                    // 2048*3584*2 = 14,680,064
    float* P  = (float*)(ws + 14680064);                          // 8*2048*256*4 = 16,777,216
    float* hx = (float*)(ws + 14680064 + 16777216);               // 524,288
    __hip_bfloat16* w3p = (__hip_bfloat16*)(ws + 31981568);       // 256*3584*2 = 1,835,008
    __hip_bfloat16* w2p = (__hip_bfloat16*)(ws + 33816576);       // 32*160*2 = 10,240

    cvt_w3p_k<<<3584, 256, 0, stream>>>(fc3w, w3p);
    cvt_w2p_k<<<20, 256, 0, stream>>>(w2, w2p);
    hipMemsetAsync(hx, 0, (size_t)2048 * 64 * sizeof(float), stream);

    for (int t = 0; t < 10; ++t) {
        conv_step_k<<<512, 256, 0, stream>>>(x, w1, w2p, a2p, t);
        fc3_mfma_k<<<dim3(32, 4, FC3_SPLITS), 256, 0, stream>>>(a2p, w3p, P);
        mgu_k<<<2048, 128, 0, stream>>>(P, wih, whh, hx);
    }
    fc5_k<<<56, 256, 0, stream>>>(hx, fc5w, out);
}

// Round 4
// 285.928 us; speedup vs baseline: 6.1324x; 2.0920x over previous
//
#include <hip/hip_runtime.h>
#include <hip/hip_bf16.h>
#include <cstdint>
#include <cstddef>

// ---------------------------------------------------------------------------
// R4: MGU -> MFMA. mgu_mfma_k: 256 blocks x 8 batches; P-reduce -> a3 bf16
//     (swizzled LDS), hq exact-bf16, gates via 16x16x32 MFMA with hi/lo
//     bf16 weight pairs (fp32-accurate weights), gate math in-register.
//     conv/fc3 unchanged from R3.
// ---------------------------------------------------------------------------

typedef __bf16 bf16x8v __attribute__((ext_vector_type(8)));
typedef float  f32x4   __attribute__((ext_vector_type(4)));

#define WAVE_FENCE() asm volatile("s_waitcnt lgkmcnt(0)" ::: "memory")

// a1 LDS layout: [12 rows][13 cols][24 elems] bf16 (16 ic used + 8 pad), per batch
#define A1_PS 24
#define A1_RS (13 * A1_PS)          // 312
#define A1_ZS (12 * A1_RS)          // 3744 = zero slot (16 zeros)
#define A1_BS 3776                  // per-batch elems (7552 B)
#define XQ_BS 176                   // padded [12][14] f32 + pad

#define FC3_K      3584             // permuted/padded K (7 Mtiles * 512)
#define FC3_KC     448
#define FC3_SPLITS 8

// ---------------- weight converts (run once per call) ----------------
// fc3 weights into permuted K-layout kp = mt*512 + (fq*16+col)*8 + nt*4 + j
__global__ __launch_bounds__(256) void cvt_w3p_k(
    const float* __restrict__ in, __hip_bfloat16* __restrict__ out)
{
    int idx = blockIdx.x * 256 + threadIdx.x;          // < 256*3584
    int n = idx / FC3_K, kp = idx % FC3_K;
    int mt = kp >> 9, r = kp & 511;
    int fq = r >> 7, col = (r >> 3) & 15, nt = (r >> 2) & 1, j = r & 3;
    int pixel = mt * 16 + fq * 4 + j, oc = nt * 16 + col;
    float v = (pixel < 110) ? in[n * 3520 + oc * 110 + pixel] : 0.f;
    out[idx] = __float2bfloat16(v);
}

// conv2 weights: w2p[oc][koff*16+ic], padded to 160 with zeros (koff 9)
__global__ __launch_bounds__(256) void cvt_w2p_k(
    const float* __restrict__ w2g, __hip_bfloat16* __restrict__ out)
{
    int idx = blockIdx.x * 256 + threadIdx.x;          // < 5120
    int oc = idx / 160, k = idx % 160;
    int koff = k >> 4, ic = k & 15;
    float v = (koff < 9) ? w2g[(oc * 16 + ic) * 9 + koff] : 0.f;
    out[idx] = __float2bfloat16(v);
}

// wih -> fragment-major hi/lo pairs: [8 nt][8 kt][2 hl][64 lane][8 e]
__global__ __launch_bounds__(256) void cvt_wihfrag_k(
    const float* __restrict__ wih, __hip_bfloat16* __restrict__ out)
{
    int idx = blockIdx.x * 256 + threadIdx.x;          // < 65536
    int e = idx & 7, lane = (idx >> 3) & 63, hl = (idx >> 9) & 1;
    int kt = (idx >> 10) & 7, nt = (idx >> 13) & 7;
    int gate = nt * 16 + (lane & 15);
    int k = kt * 32 + (lane >> 4) * 8 + e;
    float v = wih[gate * 256 + k];
    __hip_bfloat16 hi = __float2bfloat16(v);
    out[idx] = hl ? __float2bfloat16(v - __bfloat162float(hi)) : hi;
}

// whh -> fragment-major hi/lo pairs: [8 nt][2 kt][2 hl][64 lane][8 e]
__global__ __launch_bounds__(256) void cvt_whhfrag_k(
    const float* __restrict__ whh, __hip_bfloat16* __restrict__ out)
{
    int idx = blockIdx.x * 256 + threadIdx.x;          // < 16384
    int e = idx & 7, lane = (idx >> 3) & 63, hl = (idx >> 9) & 1;
    int kt = (idx >> 10) & 1, nt = (idx >> 11) & 7;
    int gate = nt * 16 + (lane & 15);
    int k = kt * 32 + (lane >> 4) * 8 + e;
    float v = whh[gate * 64 + k];
    __hip_bfloat16 hi = __float2bfloat16(v);
    out[idx] = hl ? __float2bfloat16(v - __bfloat162float(hi)) : hi;
}

// ---------------- fused quant + conv1 (VALU) + conv2 (MFMA) ----------------
__global__ __launch_bounds__(256) void conv_step_k(
    const float* __restrict__ x, const float* __restrict__ w1g,
    const __hip_bfloat16* __restrict__ w2p,
    __hip_bfloat16* __restrict__ a2p, int t)
{
    __shared__ __hip_bfloat16 a1_s[4 * A1_BS];
    __shared__ float xq_s[4 * XQ_BS];

    const int tid  = threadIdx.x;
    const int wv   = tid >> 6, lane = tid & 63;
    const int b    = blockIdx.x * 4 + wv;
    const int ab   = wv * A1_BS;
    const int xb   = wv * XQ_BS;

    const int fr  = lane & 15, fq = lane >> 4;
    const int fqh = fq >> 1,  icb = (fq & 1) * 8;

    bf16x8v bfrag[5][2];
#pragma unroll
    for (int kt = 0; kt < 5; ++kt)
#pragma unroll
        for (int nt = 0; nt < 2; ++nt)
            bfrag[kt][nt] = *(const bf16x8v*)&w2p[(nt * 16 + fr) * 160 + kt * 32 + fq * 8];

    const int ocp = lane >> 3, pg = lane & 7;
    float w1a[9], w1b[9];
#pragma unroll
    for (int k = 0; k < 9; ++k) {
        w1a[k] = w1g[(2 * ocp) * 9 + k];
        w1b[k] = w1g[(2 * ocp + 1) * 9 + k];
    }

    {
        bf16x8v z = {};
#pragma unroll
        for (int i = 0; i < 8; ++i) {
            int c = lane + i * 64;
            if (c < A1_BS / 8) *(bf16x8v*)&a1_s[ab + c * 8] = z;
        }
        float4 zf = {0.f, 0.f, 0.f, 0.f};
        if (lane < XQ_BS / 4) *(float4*)&xq_s[xb + lane * 4] = zf;
    }
    WAVE_FENCE();

#pragma unroll
    for (int pass = 0; pass < 2; ++pass) {
        int p = pass * 64 + lane;
        if (p < 110) {
            float xv = x[(size_t)b * 1100 + t * 110 + p];
            xv = fminf(fmaxf(xv, -1.f), 1.f);
            xv = rintf(xv * 128.f) * 0.0078125f;
            int h = p / 11, w = p - h * 11;
            xq_s[xb + (h + 1) * 14 + (w + 1)] = xv;
        }
    }
    WAVE_FENCE();

#pragma unroll 2
    for (int i = 0; i < 14; ++i) {
        int p = pg * 14 + i;
        if (p < 110) {
            int h = p / 11, w = p - h * 11;
            const float* xw = &xq_s[xb + h * 14 + w];
            float a0 = 0.f, a1v = 0.f;
#pragma unroll
            for (int dr = 0; dr < 3; ++dr)
#pragma unroll
                for (int dc = 0; dc < 3; ++dc) {
                    float sv = xw[dr * 14 + dc];
                    a0  += w1a[dr * 3 + dc] * sv;
                    a1v += w1b[dr * 3 + dc] * sv;
                }
            a0  = fminf(fmaxf(a0, 0.f), 1.f);
            a1v = fminf(fmaxf(a1v, 0.f), 1.f);
            __hip_bfloat162 pr;
            pr.x = __float2bfloat16(a0);
            pr.y = __float2bfloat16(a1v);
            *(__hip_bfloat162*)&a1_s[ab + (h + 1) * A1_RS + (w + 1) * A1_PS + 2 * ocp] = pr;
        }
    }
    WAVE_FENCE();

    const int d0 = fqh * 24 + icb;
    const int d1 = (fqh ? 312 : 48) + icb;
    const int d2 = 336 + fqh * 24 + icb;
    const int d3 = 624 + fqh * 24 + icb;

#pragma unroll
    for (int m = 0; m < 7; ++m) {
        int p = m * 16 + fr; if (p > 109) p = 109;
        int h = p / 11, w = p - h * 11;
        const int bm = ab + h * A1_RS + w * A1_PS;
        f32x4 acc0 = {0.f, 0.f, 0.f, 0.f}, acc1 = {0.f, 0.f, 0.f, 0.f};
        bf16x8v a;
        a = *(const bf16x8v*)&a1_s[bm + d0];
        acc0 = __builtin_amdgcn_mfma_f32_16x16x32_bf16(a, bfrag[0][0], acc0, 0, 0, 0);
        acc1 = __builtin_amdgcn_mfma_f32_16x16x32_bf16(a, bfrag[0][1], acc1, 0, 0, 0);
        a = *(const bf16x8v*)&a1_s[bm + d1];
        acc0 = __builtin_amdgcn_mfma_f32_16x16x32_bf16(a, bfrag[1][0], acc0, 0, 0, 0);
        acc1 = __builtin_amdgcn_mfma_f32_16x16x32_bf16(a, bfrag[1][1], acc1, 0, 0, 0);
        a = *(const bf16x8v*)&a1_s[bm + d2];
        acc0 = __builtin_amdgcn_mfma_f32_16x16x32_bf16(a, bfrag[2][0], acc0, 0, 0, 0);
        acc1 = __builtin_amdgcn_mfma_f32_16x16x32_bf16(a, bfrag[2][1], acc1, 0, 0, 0);
        a = *(const bf16x8v*)&a1_s[bm + d3];
        acc0 = __builtin_amdgcn_mfma_f32_16x16x32_bf16(a, bfrag[3][0], acc0, 0, 0, 0);
        acc1 = __builtin_amdgcn_mfma_f32_16x16x32_bf16(a, bfrag[3][1], acc1, 0, 0, 0);
        a = *(const bf16x8v*)&a1_s[fqh ? (ab + A1_ZS) : (bm + 672 + icb)];
        acc0 = __builtin_amdgcn_mfma_f32_16x16x32_bf16(a, bfrag[4][0], acc0, 0, 0, 0);
        acc1 = __builtin_amdgcn_mfma_f32_16x16x32_bf16(a, bfrag[4][1], acc1, 0, 0, 0);

        bf16x8v ov;
#pragma unroll
        for (int j = 0; j < 4; ++j) {
            bool valid = (m * 16 + fq * 4 + j) < 110;
            float v0 = valid ? fminf(fmaxf(acc0[j], 0.f), 1.f) : 0.f;
            float v1 = valid ? fminf(fmaxf(acc1[j], 0.f), 1.f) : 0.f;
            ov[j]     = (__bf16)v0;
            ov[4 + j] = (__bf16)v1;
        }
        *(bf16x8v*)&a2p[(size_t)b * FC3_K + m * 512 + lane * 8] = ov;
    }
}

// ---------------- fc3: bf16 MFMA split-K GEMM (K = 3584 permuted) ----------
__global__ __launch_bounds__(256) void fc3_mfma_k(
    const __hip_bfloat16* __restrict__ A,   // [2048][3584]
    const __hip_bfloat16* __restrict__ W,   // [256][3584]
    float* __restrict__ P)                  // [8][2048][256]
{
    __shared__ __hip_bfloat16 As[64 * 64];
    __shared__ __hip_bfloat16 Bs[64 * 64];

    const int tid  = threadIdx.x;
    const int wv   = tid >> 6;
    const int lane = tid & 63;
    const int m0 = blockIdx.x * 64, n0 = blockIdx.y * 64, s = blockIdx.z;
    const int wr = wv >> 1, wc = wv & 1;

    const int srow   = lane >> 3;
    const int schunk = lane & 7;
    const int swzc   = schunk ^ srow;

    const int fr = lane & 15;
    const int fq = lane >> 4;

    f32x4 zero = {0.f, 0.f, 0.f, 0.f};
    f32x4 acc[2][2];
    acc[0][0] = zero; acc[0][1] = zero; acc[1][0] = zero; acc[1][1] = zero;

    for (int kt = 0; kt < FC3_KC / 64; ++kt) {
        const int kb = s * FC3_KC + kt * 64;
#pragma unroll
        for (int i = 0; i < 2; ++i) {
            const int tr = wv * 16 + i * 8;
            const __hip_bfloat16* srcA =
                A + (size_t)(m0 + tr + srow) * FC3_K + kb + swzc * 8;
            __builtin_amdgcn_global_load_lds(
                (const __attribute__((address_space(1))) void*)srcA,
                (__attribute__((address_space(3))) void*)&As[tr * 64], 16, 0, 0);
            const __hip_bfloat16* srcB =
                W + (size_t)(n0 + tr + srow) * FC3_K + kb + swzc * 8;
            __builtin_amdgcn_global_load_lds(
                (const __attribute__((address_space(1))) void*)srcB,
                (__attribute__((address_space(3))) void*)&Bs[tr * 64], 16, 0, 0);
        }
        __syncthreads();

#pragma unroll
        for (int kk = 0; kk < 2; ++kk) {
            bf16x8v af[2], bfv[2];
#pragma unroll
            for (int mi = 0; mi < 2; ++mi) {
                const int rr = wr * 32 + mi * 16 + fr;
                const int cc = (kk * 4 + fq) ^ (rr & 7);
                af[mi] = *(const bf16x8v*)&As[rr * 64 + cc * 8];
            }
#pragma unroll
            for (int ni = 0; ni < 2; ++ni) {
                const int rr = wc * 32 + ni * 16 + fr;
                const int cc = (kk * 4 + fq) ^ (rr & 7);
                bfv[ni] = *(const bf16x8v*)&Bs[rr * 64 + cc * 8];
            }
#pragma unroll
            for (int mi = 0; mi < 2; ++mi)
#pragma unroll
                for (int ni = 0; ni < 2; ++ni)
                    acc[mi][ni] = __builtin_amdgcn_mfma_f32_16x16x32_bf16(
                        af[mi], bfv[ni], acc[mi][ni], 0, 0, 0);
        }
        __syncthreads();
    }

    float* p = P + (size_t)s * (2048 * 256)
                 + (size_t)(m0 + wr * 32) * 256 + (n0 + wc * 32);
#pragma unroll
    for (int mi = 0; mi < 2; ++mi)
#pragma unroll
        for (int ni = 0; ni < 2; ++ni)
#pragma unroll
            for (int j = 0; j < 4; ++j)
                p[(size_t)(mi * 16 + fq * 4 + j) * 256 + ni * 16 + fr] = acc[mi][ni][j];
}

// ---------------- MGU cell via MFMA ----------------
// 256 blocks x 8 batches, 4 waves. Wave wv owns f-tile wv (gates wv*16..+16)
// and n-tile wv+4. acc layout keeps gi_f/gi_n for the same (batch,gate) in
// the same lane -> gate math fully in-register.
__global__ __launch_bounds__(256) void mgu_mfma_k(
    const float* __restrict__ P, const __hip_bfloat16* __restrict__ wfi,
    const __hip_bfloat16* __restrict__ wfh, float* __restrict__ hx)
{
    __shared__ __hip_bfloat16 a3_s[16 * 256];   // rows 0..7 valid, chunk-XOR swizzled
    __shared__ __hip_bfloat16 hq_s[16 * 64];    // rows 0..7 valid, swizzled

    const int tid = threadIdx.x;
    const int wv  = tid >> 6, lane = tid & 63;
    const int fr  = lane & 15, fq = lane >> 4;
    const int b0  = blockIdx.x * 8;

    // phase 1a: reduce P -> a3 bf16 (coalesced: 64 lanes cover 2 full rows)
    {
        const int r = tid >> 5, cq = tid & 31;  // row 0..7, 8-f32 chunk 0..31
        const float* p = P + (size_t)(b0 + r) * 256 + cq * 8;
        float4 s0 = {0.f, 0.f, 0.f, 0.f}, s1 = {0.f, 0.f, 0.f, 0.f};
#pragma unroll
        for (int s = 0; s < FC3_SPLITS; ++s) {
            float4 v0 = *(const float4*)&p[(size_t)s * 524288];
            float4 v1 = *(const float4*)&p[(size_t)s * 524288 + 4];
            s0.x += v0.x; s0.y += v0.y; s0.z += v0.z; s0.w += v0.w;
            s1.x += v1.x; s1.y += v1.y; s1.z += v1.z; s1.w += v1.w;
        }
        bf16x8v o;
        o[0] = (__bf16)fminf(fmaxf(s0.x, 0.f), 1.f);
        o[1] = (__bf16)fminf(fmaxf(s0.y, 0.f), 1.f);
        o[2] = (__bf16)fminf(fmaxf(s0.z, 0.f), 1.f);
        o[3] = (__bf16)fminf(fmaxf(s0.w, 0.f), 1.f);
        o[4] = (__bf16)fminf(fmaxf(s1.x, 0.f), 1.f);
        o[5] = (__bf16)fminf(fmaxf(s1.y, 0.f), 1.f);
        o[6] = (__bf16)fminf(fmaxf(s1.z, 0.f), 1.f);
        o[7] = (__bf16)fminf(fmaxf(s1.w, 0.f), 1.f);
        *(bf16x8v*)&a3_s[r * 256 + (cq ^ (r & 7)) * 8] = o;
    }
    // phase 1b: hq = quantize(hx) (exact in bf16: k/128, |k|<=128)
    for (int i = tid; i < 512; i += 256) {
        int r = i >> 6, c = i & 63;
        float v = hx[(size_t)(b0 + r) * 64 + c];
        v = fminf(fmaxf(v, -1.f), 1.f);
        v = rintf(v * 128.f) * 0.0078125f;
        hq_s[r * 64 + (((c >> 3) ^ (r & 7)) << 3) + (c & 7)] = __float2bfloat16(v);
    }
    __syncthreads();

    f32x4 accF  = {0.f, 0.f, 0.f, 0.f};   // gi_f + gh_f
    f32x4 accNi = {0.f, 0.f, 0.f, 0.f};   // gi_n
    f32x4 accNh = {0.f, 0.f, 0.f, 0.f};   // gh_n
    const int ntf = wv, ntn = wv + 4;

#pragma unroll
    for (int kt = 0; kt < 8; ++kt) {
        bf16x8v a = *(const bf16x8v*)&a3_s[fr * 256 + (((kt * 4 + fq) ^ (fr & 7))) * 8];
        bf16x8v bfh = *(const bf16x8v*)&wfi[(((ntf * 8 + kt) * 2 + 0) * 64 + lane) * 8];
        bf16x8v bfl = *(const bf16x8v*)&wfi[(((ntf * 8 + kt) * 2 + 1) * 64 + lane) * 8];
        bf16x8v bnh = *(const bf16x8v*)&wfi[(((ntn * 8 + kt) * 2 + 0) * 64 + lane) * 8];
        bf16x8v bnl = *(const bf16x8v*)&wfi[(((ntn * 8 + kt) * 2 + 1) * 64 + lane) * 8];
        accF  = __builtin_amdgcn_mfma_f32_16x16x32_bf16(a, bfh, accF, 0, 0, 0);
        accF  = __builtin_amdgcn_mfma_f32_16x16x32_bf16(a, bfl, accF, 0, 0, 0);
        accNi = __builtin_amdgcn_mfma_f32_16x16x32_bf16(a, bnh, accNi, 0, 0, 0);
        accNi = __builtin_amdgcn_mfma_f32_16x16x32_bf16(a, bnl, accNi, 0, 0, 0);
    }
#pragma unroll
    for (int kt = 0; kt < 2; ++kt) {
        bf16x8v a = *(const bf16x8v*)&hq_s[fr * 64 + (((kt * 4 + fq) ^ (fr & 7))) * 8];
        bf16x8v bfh = *(const bf16x8v*)&wfh[(((ntf * 2 + kt) * 2 + 0) * 64 + lane) * 8];
        bf16x8v bfl = *(const bf16x8v*)&wfh[(((ntf * 2 + kt) * 2 + 1) * 64 + lane) * 8];
        bf16x8v bnh = *(const bf16x8v*)&wfh[(((ntn * 2 + kt) * 2 + 0) * 64 + lane) * 8];
        bf16x8v bnl = *(const bf16x8v*)&wfh[(((ntn * 2 + kt) * 2 + 1) * 64 + lane) * 8];
        accF  = __builtin_amdgcn_mfma_f32_16x16x32_bf16(a, bfh, accF, 0, 0, 0);
        accF  = __builtin_amdgcn_mfma_f32_16x16x32_bf16(a, bfl, accF, 0, 0, 0);
        accNh = __builtin_amdgcn_mfma_f32_16x16x32_bf16(a, bnh, accNh, 0, 0, 0);
        accNh = __builtin_amdgcn_mfma_f32_16x16x32_bf16(a, bnl, accNh, 0, 0, 0);
    }

    // epilogue: acc row = fq*4+jj = batch (valid < 8), col = fr = gate within tile
    if (fq < 2) {
#pragma unroll
        for (int jj = 0; jj < 4; ++jj) {
            int b = fq * 4 + jj;
            float f = fminf(fmaxf(0.5f * accF[jj] + 0.5f, 0.f), 1.f);
            float n = fminf(fmaxf(accNi[jj] + f * accNh[jj], -1.f), 1.f);
            int j = wv * 16 + fr;
            float hq = __bfloat162float(
                hq_s[b * 64 + (((j >> 3) ^ (b & 7)) << 3) + (j & 7)]);
            hx[(size_t)(b0 + b) * 64 + j] = (1.f - f) * n + f * hq;
        }
    }
}

// ---------------- fc5 ----------------
__global__ __launch_bounds__(256) void fc5_k(
    const float* __restrict__ hx, const float* __restrict__ w,
    float* __restrict__ out)
{
    int idx = blockIdx.x * 256 + threadIdx.x;
    if (idx < 2048 * 7) {
        int b = idx / 7, c = idx % 7;
        const float* hr = &hx[b * 64];
        const float* wr = &w[c * 64];
        float acc = 0.f;
#pragma unroll
        for (int k = 0; k < 64; ++k) acc += hr[k] * wr[k];
        out[idx] = acc;
    }
}

extern "C" void kernel_launch(void* const* d_in, const int* in_sizes, int n_in,
                              void* d_out, int out_size, void* d_ws, size_t ws_size,
                              hipStream_t stream)
{
    const float* x    = (const float*)d_in[0];
    const float* w1   = (const float*)d_in[1];
    const float* w2   = (const float*)d_in[2];
    const float* fc3w = (const float*)d_in[3];
    const float* wih  = (const float*)d_in[4];
    const float* whh  = (const float*)d_in[5];
    const float* fc5w = (const float*)d_in[6];
    float* out = (float*)d_out;

    char* ws = (char*)d_ws;
    __hip_bfloat16* a2p = (__hip_bfloat16*)ws;                    // 14,680,064 B
    float* P  = (float*)(ws + 14680064);                          // 16,777,216 B
    float* hx = (float*)(ws + 31457280);                          //    524,288 B
    __hip_bfloat16* w3p = (__hip_bfloat16*)(ws + 31981568);       //  1,835,008 B
    __hip_bfloat16* w2p = (__hip_bfloat16*)(ws + 33816576);       //     10,240 B
    __hip_bfloat16* wfi = (__hip_bfloat16*)(ws + 33826816);       //    131,072 B
    __hip_bfloat16* wfh = (__hip_bfloat16*)(ws + 33957888);       //     32,768 B

    cvt_w3p_k<<<3584, 256, 0, stream>>>(fc3w, w3p);
    cvt_w2p_k<<<20, 256, 0, stream>>>(w2, w2p);
    cvt_wihfrag_k<<<256, 256, 0, stream>>>(wih, wfi);
    cvt_whhfrag_k<<<64, 256, 0, stream>>>(whh, wfh);
    hipMemsetAsync(hx, 0, (size_t)2048 * 64 * sizeof(float), stream);

    for (int t = 0; t < 10; ++t) {
        conv_step_k<<<512, 256, 0, stream>>>(x, w1, w2p, a2p, t);
        fc3_mfma_k<<<dim3(32, 4, FC3_SPLITS), 256, 0, stream>>>(a2p, w3p, P);
        mgu_mfma_k<<<256, 256, 0, stream>>>(P, wfi, wfh, hx);
    }
    fc5_k<<<56, 256, 0, stream>>>(hx, fc5w, out);
}

// Round 5
// 120.806 us; speedup vs baseline: 14.5143x; 2.3668x over previous
//
#include <hip/hip_runtime.h>
#include <hip/hip_bf16.h>
#include <cstdint>
#include <cstddef>

// ---------------------------------------------------------------------------
// R5: de-serialize the scan. conv (all 10 steps, one launch) -> fc3 (one
//     20480x256x3584 GEMM, clip in epilogue, a3 bf16, no split-K/P) ->
//     mgu_all (10 sequential MGU steps + fc5 in one kernel; hx in LDS,
//     weight fragments hoisted in VGPRs). 7 dispatches total.
// ---------------------------------------------------------------------------

typedef __bf16 bf16x8v __attribute__((ext_vector_type(8)));
typedef float  f32x4   __attribute__((ext_vector_type(4)));

#define WAVE_FENCE() asm volatile("s_waitcnt lgkmcnt(0)" ::: "memory")

#define A1_PS 24
#define A1_RS (13 * A1_PS)          // 312
#define A1_ZS (12 * A1_RS)          // 3744 = zero slot
#define A1_BS 3776                  // per-batch elems (7552 B)
#define XQ_BS 176

#define FC3_K 3584                  // permuted/padded K (7 Mtiles * 512)

// ---------------- weight converts (run once per call) ----------------
// fc3 weights into permuted K-layout kp = mt*512 + (fq*16+col)*8 + nt*4 + j
__global__ __launch_bounds__(256) void cvt_w3p_k(
    const float* __restrict__ in, __hip_bfloat16* __restrict__ out)
{
    int idx = blockIdx.x * 256 + threadIdx.x;          // < 256*3584
    int n = idx / FC3_K, kp = idx % FC3_K;
    int mt = kp >> 9, r = kp & 511;
    int fq = r >> 7, col = (r >> 3) & 15, nt = (r >> 2) & 1, j = r & 3;
    int pixel = mt * 16 + fq * 4 + j, oc = nt * 16 + col;
    float v = (pixel < 110) ? in[n * 3520 + oc * 110 + pixel] : 0.f;
    out[idx] = __float2bfloat16(v);
}

// conv2 weights: w2p[oc][koff*16+ic], padded to 160 with zeros
__global__ __launch_bounds__(256) void cvt_w2p_k(
    const float* __restrict__ w2g, __hip_bfloat16* __restrict__ out)
{
    int idx = blockIdx.x * 256 + threadIdx.x;          // < 5120
    int oc = idx / 160, k = idx % 160;
    int koff = k >> 4, ic = k & 15;
    float v = (koff < 9) ? w2g[(oc * 16 + ic) * 9 + koff] : 0.f;
    out[idx] = __float2bfloat16(v);
}

// wih -> fragment-major hi/lo pairs: [8 nt][8 kt][2 hl][64 lane][8 e]
__global__ __launch_bounds__(256) void cvt_wihfrag_k(
    const float* __restrict__ wih, __hip_bfloat16* __restrict__ out)
{
    int idx = blockIdx.x * 256 + threadIdx.x;          // < 65536
    int e = idx & 7, lane = (idx >> 3) & 63, hl = (idx >> 9) & 1;
    int kt = (idx >> 10) & 7, nt = (idx >> 13) & 7;
    int gate = nt * 16 + (lane & 15);
    int k = kt * 32 + (lane >> 4) * 8 + e;
    float v = wih[gate * 256 + k];
    __hip_bfloat16 hi = __float2bfloat16(v);
    out[idx] = hl ? __float2bfloat16(v - __bfloat162float(hi)) : hi;
}

// whh -> fragment-major hi/lo pairs: [8 nt][2 kt][2 hl][64 lane][8 e]
__global__ __launch_bounds__(256) void cvt_whhfrag_k(
    const float* __restrict__ whh, __hip_bfloat16* __restrict__ out)
{
    int idx = blockIdx.x * 256 + threadIdx.x;          // < 16384
    int e = idx & 7, lane = (idx >> 3) & 63, hl = (idx >> 9) & 1;
    int kt = (idx >> 10) & 1, nt = (idx >> 11) & 7;
    int gate = nt * 16 + (lane & 15);
    int k = kt * 32 + (lane >> 4) * 8 + e;
    float v = whh[gate * 64 + k];
    __hip_bfloat16 hi = __float2bfloat16(v);
    out[idx] = hl ? __float2bfloat16(v - __bfloat162float(hi)) : hi;
}

// ---------------- all-steps fused quant + conv1 + conv2 ----------------
// grid 5120 = 10 t * 512; block = 4 waves, wave = 1 (batch, t), no barriers.
__global__ __launch_bounds__(256) void conv_all_k(
    const float* __restrict__ x, const float* __restrict__ w1g,
    const __hip_bfloat16* __restrict__ w2p,
    __hip_bfloat16* __restrict__ a2p)
{
    __shared__ __hip_bfloat16 a1_s[4 * A1_BS];
    __shared__ float xq_s[4 * XQ_BS];

    const int tid  = threadIdx.x;
    const int wv   = tid >> 6, lane = tid & 63;
    const int t    = blockIdx.x >> 9;
    const int b    = (blockIdx.x & 511) * 4 + wv;
    const int ab   = wv * A1_BS;
    const int xb   = wv * XQ_BS;

    const int fr  = lane & 15, fq = lane >> 4;
    const int fqh = fq >> 1,  icb = (fq & 1) * 8;

    bf16x8v bfrag[5][2];
#pragma unroll
    for (int kt = 0; kt < 5; ++kt)
#pragma unroll
        for (int nt = 0; nt < 2; ++nt)
            bfrag[kt][nt] = *(const bf16x8v*)&w2p[(nt * 16 + fr) * 160 + kt * 32 + fq * 8];

    const int ocp = lane >> 3, pg = lane & 7;
    float w1a[9], w1b[9];
#pragma unroll
    for (int k = 0; k < 9; ++k) {
        w1a[k] = w1g[(2 * ocp) * 9 + k];
        w1b[k] = w1g[(2 * ocp + 1) * 9 + k];
    }

    {
        bf16x8v z = {};
#pragma unroll
        for (int i = 0; i < 8; ++i) {
            int c = lane + i * 64;
            if (c < A1_BS / 8) *(bf16x8v*)&a1_s[ab + c * 8] = z;
        }
        float4 zf = {0.f, 0.f, 0.f, 0.f};
        if (lane < XQ_BS / 4) *(float4*)&xq_s[xb + lane * 4] = zf;
    }
    WAVE_FENCE();

#pragma unroll
    for (int pass = 0; pass < 2; ++pass) {
        int p = pass * 64 + lane;
        if (p < 110) {
            float xv = x[(size_t)b * 1100 + t * 110 + p];
            xv = fminf(fmaxf(xv, -1.f), 1.f);
            xv = rintf(xv * 128.f) * 0.0078125f;
            int h = p / 11, w = p - h * 11;
            xq_s[xb + (h + 1) * 14 + (w + 1)] = xv;
        }
    }
    WAVE_FENCE();

#pragma unroll 2
    for (int i = 0; i < 14; ++i) {
        int p = pg * 14 + i;
        if (p < 110) {
            int h = p / 11, w = p - h * 11;
            const float* xw = &xq_s[xb + h * 14 + w];
            float a0 = 0.f, a1v = 0.f;
#pragma unroll
            for (int dr = 0; dr < 3; ++dr)
#pragma unroll
                for (int dc = 0; dc < 3; ++dc) {
                    float sv = xw[dr * 14 + dc];
                    a0  += w1a[dr * 3 + dc] * sv;
                    a1v += w1b[dr * 3 + dc] * sv;
                }
            a0  = fminf(fmaxf(a0, 0.f), 1.f);
            a1v = fminf(fmaxf(a1v, 0.f), 1.f);
            __hip_bfloat162 pr;
            pr.x = __float2bfloat16(a0);
            pr.y = __float2bfloat16(a1v);
            *(__hip_bfloat162*)&a1_s[ab + (h + 1) * A1_RS + (w + 1) * A1_PS + 2 * ocp] = pr;
        }
    }
    WAVE_FENCE();

    const int d0 = fqh * 24 + icb;
    const int d1 = (fqh ? 312 : 48) + icb;
    const int d2 = 336 + fqh * 24 + icb;
    const int d3 = 624 + fqh * 24 + icb;

#pragma unroll
    for (int m = 0; m < 7; ++m) {
        int p = m * 16 + fr; if (p > 109) p = 109;
        int h = p / 11, w = p - h * 11;
        const int bm = ab + h * A1_RS + w * A1_PS;
        f32x4 acc0 = {0.f, 0.f, 0.f, 0.f}, acc1 = {0.f, 0.f, 0.f, 0.f};
        bf16x8v a;
        a = *(const bf16x8v*)&a1_s[bm + d0];
        acc0 = __builtin_amdgcn_mfma_f32_16x16x32_bf16(a, bfrag[0][0], acc0, 0, 0, 0);
        acc1 = __builtin_amdgcn_mfma_f32_16x16x32_bf16(a, bfrag[0][1], acc1, 0, 0, 0);
        a = *(const bf16x8v*)&a1_s[bm + d1];
        acc0 = __builtin_amdgcn_mfma_f32_16x16x32_bf16(a, bfrag[1][0], acc0, 0, 0, 0);
        acc1 = __builtin_amdgcn_mfma_f32_16x16x32_bf16(a, bfrag[1][1], acc1, 0, 0, 0);
        a = *(const bf16x8v*)&a1_s[bm + d2];
        acc0 = __builtin_amdgcn_mfma_f32_16x16x32_bf16(a, bfrag[2][0], acc0, 0, 0, 0);
        acc1 = __builtin_amdgcn_mfma_f32_16x16x32_bf16(a, bfrag[2][1], acc1, 0, 0, 0);
        a = *(const bf16x8v*)&a1_s[bm + d3];
        acc0 = __builtin_amdgcn_mfma_f32_16x16x32_bf16(a, bfrag[3][0], acc0, 0, 0, 0);
        acc1 = __builtin_amdgcn_mfma_f32_16x16x32_bf16(a, bfrag[3][1], acc1, 0, 0, 0);
        a = *(const bf16x8v*)&a1_s[fqh ? (ab + A1_ZS) : (bm + 672 + icb)];
        acc0 = __builtin_amdgcn_mfma_f32_16x16x32_bf16(a, bfrag[4][0], acc0, 0, 0, 0);
        acc1 = __builtin_amdgcn_mfma_f32_16x16x32_bf16(a, bfrag[4][1], acc1, 0, 0, 0);

        bf16x8v ov;
#pragma unroll
        for (int j = 0; j < 4; ++j) {
            bool valid = (m * 16 + fq * 4 + j) < 110;
            float v0 = valid ? fminf(fmaxf(acc0[j], 0.f), 1.f) : 0.f;
            float v1 = valid ? fminf(fmaxf(acc1[j], 0.f), 1.f) : 0.f;
            ov[j]     = (__bf16)v0;
            ov[4 + j] = (__bf16)v1;
        }
        *(bf16x8v*)&a2p[(size_t)(t * 2048 + b) * FC3_K + m * 512 + lane * 8] = ov;
    }
}

// ---------------- fc3: one GEMM [20480 x 3584] * [3584 x 256] ----------
// 128x64 tile, 4 waves (2x2, each 64x32), BK=64, 56 K-steps. grid (160,4).
// Epilogue: clip [0,1] -> bf16 a3.
__global__ __launch_bounds__(256) void fc3_all_k(
    const __hip_bfloat16* __restrict__ A,   // [20480][3584]
    const __hip_bfloat16* __restrict__ W,   // [256][3584]
    __hip_bfloat16* __restrict__ a3)        // [20480][256]
{
    __shared__ __hip_bfloat16 As[128 * 64];
    __shared__ __hip_bfloat16 Bs[64 * 64];

    const int tid  = threadIdx.x;
    const int wv   = tid >> 6;
    const int lane = tid & 63;
    const int m0 = blockIdx.x * 128, n0 = blockIdx.y * 64;
    const int wr = wv >> 1, wc = wv & 1;

    const int srow   = lane >> 3;
    const int schunk = lane & 7;
    const int swzc   = schunk ^ srow;

    const int fr = lane & 15;
    const int fq = lane >> 4;

    f32x4 acc[4][2];
#pragma unroll
    for (int mi = 0; mi < 4; ++mi)
#pragma unroll
        for (int ni = 0; ni < 2; ++ni)
            acc[mi][ni] = (f32x4){0.f, 0.f, 0.f, 0.f};

    for (int kt = 0; kt < 56; ++kt) {
        const int kb = kt * 64;
#pragma unroll
        for (int i = 0; i < 4; ++i) {
            const int tr = wv * 32 + i * 8;
            const __hip_bfloat16* srcA =
                A + (size_t)(m0 + tr + srow) * FC3_K + kb + swzc * 8;
            __builtin_amdgcn_global_load_lds(
                (const __attribute__((address_space(1))) void*)srcA,
                (__attribute__((address_space(3))) void*)&As[tr * 64], 16, 0, 0);
        }
#pragma unroll
        for (int i = 0; i < 2; ++i) {
            const int tr = wv * 16 + i * 8;
            const __hip_bfloat16* srcB =
                W + (size_t)(n0 + tr + srow) * FC3_K + kb + swzc * 8;
            __builtin_amdgcn_global_load_lds(
                (const __attribute__((address_space(1))) void*)srcB,
                (__attribute__((address_space(3))) void*)&Bs[tr * 64], 16, 0, 0);
        }
        __syncthreads();

#pragma unroll
        for (int kk = 0; kk < 2; ++kk) {
            bf16x8v af[4], bfv[2];
#pragma unroll
            for (int mi = 0; mi < 4; ++mi) {
                const int rr = wr * 64 + mi * 16 + fr;
                const int cc = (kk * 4 + fq) ^ (rr & 7);
                af[mi] = *(const bf16x8v*)&As[rr * 64 + cc * 8];
            }
#pragma unroll
            for (int ni = 0; ni < 2; ++ni) {
                const int rr = wc * 32 + ni * 16 + fr;
                const int cc = (kk * 4 + fq) ^ (rr & 7);
                bfv[ni] = *(const bf16x8v*)&Bs[rr * 64 + cc * 8];
            }
#pragma unroll
            for (int mi = 0; mi < 4; ++mi)
#pragma unroll
                for (int ni = 0; ni < 2; ++ni)
                    acc[mi][ni] = __builtin_amdgcn_mfma_f32_16x16x32_bf16(
                        af[mi], bfv[ni], acc[mi][ni], 0, 0, 0);
        }
        __syncthreads();
    }

#pragma unroll
    for (int mi = 0; mi < 4; ++mi)
#pragma unroll
        for (int ni = 0; ni < 2; ++ni)
#pragma unroll
            for (int j = 0; j < 4; ++j) {
                int row = m0 + wr * 64 + mi * 16 + fq * 4 + j;
                int col = n0 + wc * 32 + ni * 16 + fr;
                float v = fminf(fmaxf(acc[mi][ni][j], 0.f), 1.f);
                a3[(size_t)row * 256 + col] = __float2bfloat16(v);
            }
}

// ---------------- MGU all steps + fc5, one kernel ----------------
// 128 blocks x 16 batches, 4 waves. hx lives in LDS; weight fragments in
// VGPRs across the 10-step loop. Per-batch recurrence is block-local.
__global__ __launch_bounds__(256, 1) void mgu_all_k(
    const __hip_bfloat16* __restrict__ a3,  // [10*2048][256]
    const __hip_bfloat16* __restrict__ wfi, const __hip_bfloat16* __restrict__ wfh,
    const float* __restrict__ w5, float* __restrict__ out)
{
    __shared__ __hip_bfloat16 a3_s[16 * 256];   // chunk-XOR swizzled
    __shared__ __hip_bfloat16 hq_s[16 * 64];    // swizzled
    __shared__ float hx_s[16 * 64];
    __shared__ float w5_s[7 * 64];

    const int tid = threadIdx.x;
    const int wv  = tid >> 6, lane = tid & 63;
    const int fr  = lane & 15, fq = lane >> 4;
    const int b0  = blockIdx.x * 16;
    const int ntf = wv, ntn = wv + 4;

    // hoist all weight fragments into VGPRs (held across the 10 steps)
    bf16x8v wiF[8][2], wiN[8][2], whF[2][2], whN[2][2];
#pragma unroll
    for (int kt = 0; kt < 8; ++kt)
#pragma unroll
        for (int hl = 0; hl < 2; ++hl) {
            wiF[kt][hl] = *(const bf16x8v*)&wfi[(((ntf * 8 + kt) * 2 + hl) * 64 + lane) * 8];
            wiN[kt][hl] = *(const bf16x8v*)&wfi[(((ntn * 8 + kt) * 2 + hl) * 64 + lane) * 8];
        }
#pragma unroll
    for (int kt = 0; kt < 2; ++kt)
#pragma unroll
        for (int hl = 0; hl < 2; ++hl) {
            whF[kt][hl] = *(const bf16x8v*)&wfh[(((ntf * 2 + kt) * 2 + hl) * 64 + lane) * 8];
            whN[kt][hl] = *(const bf16x8v*)&wfh[(((ntn * 2 + kt) * 2 + hl) * 64 + lane) * 8];
        }

    for (int i = tid; i < 16 * 64; i += 256) hx_s[i] = 0.f;
    for (int i = tid; i < 7 * 64; i += 256) w5_s[i] = w5[i];
    __syncthreads();

    for (int t = 0; t < 10; ++t) {
        // stage a3 slice (16 rows x 256) coalesced, XOR-swizzled
#pragma unroll
        for (int pass = 0; pass < 2; ++pass) {
            int i = pass * 256 + tid;               // 0..511
            int r = i >> 5, cq = i & 31;
            bf16x8v v = *(const bf16x8v*)&a3[((size_t)(t * 2048 + b0 + r)) * 256 + cq * 8];
            *(bf16x8v*)&a3_s[r * 256 + ((cq ^ (r & 7)) * 8)] = v;
        }
        // hq = quantize(hx) (exact in bf16: k/128)
#pragma unroll
        for (int pass = 0; pass < 4; ++pass) {
            int i = pass * 256 + tid;               // 0..1023
            int r = i >> 6, c = i & 63;
            float v = hx_s[r * 64 + c];
            v = fminf(fmaxf(v, -1.f), 1.f);
            v = rintf(v * 128.f) * 0.0078125f;
            hq_s[r * 64 + (((c >> 3) ^ (r & 7)) << 3) + (c & 7)] = __float2bfloat16(v);
        }
        __syncthreads();

        f32x4 accF  = {0.f, 0.f, 0.f, 0.f};
        f32x4 accNi = {0.f, 0.f, 0.f, 0.f};
        f32x4 accNh = {0.f, 0.f, 0.f, 0.f};
#pragma unroll
        for (int kt = 0; kt < 8; ++kt) {
            bf16x8v a = *(const bf16x8v*)&a3_s[fr * 256 + (((kt * 4 + fq) ^ (fr & 7)) * 8)];
            accF  = __builtin_amdgcn_mfma_f32_16x16x32_bf16(a, wiF[kt][0], accF, 0, 0, 0);
            accF  = __builtin_amdgcn_mfma_f32_16x16x32_bf16(a, wiF[kt][1], accF, 0, 0, 0);
            accNi = __builtin_amdgcn_mfma_f32_16x16x32_bf16(a, wiN[kt][0], accNi, 0, 0, 0);
            accNi = __builtin_amdgcn_mfma_f32_16x16x32_bf16(a, wiN[kt][1], accNi, 0, 0, 0);
        }
#pragma unroll
        for (int kt = 0; kt < 2; ++kt) {
            bf16x8v a = *(const bf16x8v*)&hq_s[fr * 64 + (((kt * 4 + fq) ^ (fr & 7)) * 8)];
            accF  = __builtin_amdgcn_mfma_f32_16x16x32_bf16(a, whF[kt][0], accF, 0, 0, 0);
            accF  = __builtin_amdgcn_mfma_f32_16x16x32_bf16(a, whF[kt][1], accF, 0, 0, 0);
            accNh = __builtin_amdgcn_mfma_f32_16x16x32_bf16(a, whN[kt][0], accNh, 0, 0, 0);
            accNh = __builtin_amdgcn_mfma_f32_16x16x32_bf16(a, whN[kt][1], accNh, 0, 0, 0);
        }

        // epilogue: row = fq*4+j = batch, col = fr = gate within 16-wide tile
        const int j5 = wv * 16 + fr;
#pragma unroll
        for (int j = 0; j < 4; ++j) {
            int b = fq * 4 + j;
            float f = fminf(fmaxf(0.5f * accF[j] + 0.5f, 0.f), 1.f);
            float n = fminf(fmaxf(accNi[j] + f * accNh[j], -1.f), 1.f);
            float hq = __bfloat162float(
                hq_s[b * 64 + ((((j5) >> 3) ^ (b & 7)) << 3) + (j5 & 7)]);
            hx_s[b * 64 + j5] = (1.f - f) * n + f * hq;
        }
        __syncthreads();
    }

    // fc5: out[b0+b][c] = hx[b] . w5[c]
    if (tid < 112) {
        int b = tid / 7, c = tid % 7;
        float acc = 0.f;
#pragma unroll
        for (int k = 0; k < 64; ++k) acc += hx_s[b * 64 + k] * w5_s[c * 64 + k];
        out[(size_t)(b0 + b) * 7 + c] = acc;
    }
}

extern "C" void kernel_launch(void* const* d_in, const int* in_sizes, int n_in,
                              void* d_out, int out_size, void* d_ws, size_t ws_size,
                              hipStream_t stream)
{
    const float* x    = (const float*)d_in[0];
    const float* w1   = (const float*)d_in[1];
    const float* w2   = (const float*)d_in[2];
    const float* fc3w = (const float*)d_in[3];
    const float* wih  = (const float*)d_in[4];
    const float* whh  = (const float*)d_in[5];
    const float* fc5w = (const float*)d_in[6];
    float* out = (float*)d_out;

    char* ws = (char*)d_ws;
    __hip_bfloat16* a2p = (__hip_bfloat16*)ws;                     // 10*2048*3584*2 = 146,800,640
    __hip_bfloat16* a3  = (__hip_bfloat16*)(ws + 146800640);       // 20480*256*2    =  10,485,760
    __hip_bfloat16* w3p = (__hip_bfloat16*)(ws + 157286400);       //                   1,835,008
    __hip_bfloat16* w2p = (__hip_bfloat16*)(ws + 159121408);       //                      10,240
    __hip_bfloat16* wfi = (__hip_bfloat16*)(ws + 159131648);       //                     131,072
    __hip_bfloat16* wfh = (__hip_bfloat16*)(ws + 159262720);       //                      32,768

    cvt_w3p_k<<<3584, 256, 0, stream>>>(fc3w, w3p);
    cvt_w2p_k<<<20, 256, 0, stream>>>(w2, w2p);
    cvt_wihfrag_k<<<256, 256, 0, stream>>>(wih, wfi);
    cvt_whhfrag_k<<<64, 256, 0, stream>>>(whh, wfh);

    conv_all_k<<<5120, 256, 0, stream>>>(x, w1, w2p, a2p);
    fc3_all_k<<<dim3(160, 4), 256, 0, stream>>>(a2p, w3p, a3);
    mgu_all_k<<<128, 256, 0, stream>>>(a3, wfi, wfh, fc5w, out);
}